// Round 4
// baseline (259.507 us; speedup 1.0000x reference)
//
#include <hip/hip_runtime.h>
#include <math.h>

// Problem constants: U=4 users, NT=8 antennas, BATCH*CWH = 6,291,456 fp32 per plane.
#define UU 4
#define NTT 8
#define BC4 1572864            // (BATCH*CWH)/4 float4 groups per plane
#define THREADS 256
#define TILE 4                 // float4 positions per thread
#define NBLOCKS (BC4 / (THREADS * TILE))   // 1536, exact cover

typedef float f32x4 __attribute__((ext_vector_type(4)));

// Single fused kernel. 4x4 mixing matrix recomputed per-thread from the tiny
// (160 B, LLC-resident) W/H/P/stddev inputs — negligible vs 768 B/thread of
// streaming traffic.
//
// Round-2 change (re-rerun; two infra failures): loads are PLAIN (cached).
// Inputs (~186 MB) nearly fit the 256 MB Infinity Cache and are re-read every
// graph replay; the previous nontemporal hint told the LLC not to retain them
// (FETCH_SIZE showed 98 MB of HBM re-fetch per dispatch). Stores stay
// nontemporal: output has zero reuse and is re-poisoned each iteration, and
// bypassing protects LLC input residency.
//
// Math (matches reference):
//   out[u] = (sum_v c[u][v] * x[v]) + nc[u] * noise[u]
//   c[u][v] = sqrtP[v] * (sum_n H[n,u] W[n,v]) / amp[u]
//   nc[u]   = stddev[u] / amp[u],  amp[u] = sqrtP[u] * sum_n H[n,u] W[n,u]
__global__ __launch_bounds__(THREADS) void mix_kernel(
    const f32x4* __restrict__ x4,   // [U][BC4]
    const f32x4* __restrict__ n4,   // [U][BC4]
    const float* __restrict__ W,    // [NT][U]
    const float* __restrict__ H,    // [NT][U]
    const float* __restrict__ P,    // [U]
    const float* __restrict__ stddev, // [U]
    f32x4* __restrict__ o4)         // [U][BC4]
{
    // ---- per-thread coefficient computation (uniform addresses -> SGPRs) ----
    float c[UU][UU], nc[UU];
    {
        float sqrtP[UU];
#pragma unroll
        for (int v = 0; v < UU; ++v) sqrtP[v] = sqrtf(P[v]);
#pragma unroll
        for (int u = 0; u < UU; ++u) {
            float hw = 0.0f;
#pragma unroll
            for (int n = 0; n < NTT; ++n) hw += H[n * UU + u] * W[n * UU + u];
            const float inv_amp = 1.0f / (sqrtP[u] * hw);
#pragma unroll
            for (int v = 0; v < UU; ++v) {
                float m = 0.0f;
#pragma unroll
                for (int n = 0; n < NTT; ++n) m += H[n * UU + u] * W[n * UU + v];
                c[u][v] = m * sqrtP[v] * inv_amp;
            }
            nc[u] = stddev[u] * inv_amp;
        }
    }

    // ---- memory-bound mixing: 16 KB contiguous per plane per block ----
    const int base = blockIdx.x * (THREADS * TILE) + threadIdx.x;
#pragma unroll
    for (int j = 0; j < TILE; ++j) {
        const int i4 = base + j * THREADS;

        // PLAIN cached loads: let L2/LLC retain inputs across graph replays.
        f32x4 xv[UU];
#pragma unroll
        for (int v = 0; v < UU; ++v)
            xv[v] = x4[v * BC4 + i4];

#pragma unroll
        for (int u = 0; u < UU; ++u) {
            const f32x4 nv = n4[u * BC4 + i4];
            f32x4 acc = nc[u] * nv;
#pragma unroll
            for (int v = 0; v < UU; ++v)
                acc += c[u][v] * xv[v];
            // out has zero reuse: stream past L2/LLC (also avoids evicting inputs).
            __builtin_nontemporal_store(acc, &o4[u * BC4 + i4]);
        }
    }
}

extern "C" void kernel_launch(void* const* d_in, const int* in_sizes, int n_in,
                              void* d_out, int out_size, void* d_ws, size_t ws_size,
                              hipStream_t stream) {
    const float* x      = (const float*)d_in[0];
    const float* W      = (const float*)d_in[1];
    const float* H      = (const float*)d_in[2];
    const float* P      = (const float*)d_in[3];
    const float* stddev = (const float*)d_in[4];
    const float* noise  = (const float*)d_in[5];
    float* out = (float*)d_out;

    mix_kernel<<<NBLOCKS, THREADS, 0, stream>>>(
        (const f32x4*)x, (const f32x4*)noise, W, H, P, stddev, (f32x4*)out);
}

// Round 5
// 234.554 us; speedup vs baseline: 1.1064x; 1.1064x over previous
//
#include <hip/hip_runtime.h>
#include <math.h>

// Problem constants: U=4 users, NT=8 antennas, BATCH*CWH = 6,291,456 fp32 per plane.
#define UU 4
#define NTT 8
#define BC4 1572864            // (BATCH*CWH)/4 float4 groups per plane
#define THREADS 256
#define NBLOCKS (BC4 / THREADS)   // 6144 blocks, TILE=1, exact cover

typedef float f32x4 __attribute__((ext_vector_type(4)));

// Single fused kernel, full-nontemporal streaming.
//
// Round-4 post-mortem: cached loads were 1.67x SLOWER than nontemporal
// (102 us vs 61 us) with IDENTICAL FETCH_SIZE (98.35 MB) -> the nt hint
// doesn't affect LLC retention (harness re-poison evicts half the inputs
// regardless); it bypasses L1/L2 allocation and that path streams faster.
// Reverted to nt loads.
//
// Round-5 change: occupancy was 31% (1536 blocks = only 24 waves/CU of
// work). TILE 4 -> 1, grid 1536 -> 6144 blocks (96 waves/CU of work) to
// keep full wave residency and more loads in flight on the latency-exposed
// read path. Loads all issued before any dependent store.
//
// Math (matches reference):
//   out[u] = (sum_v c[u][v] * x[v]) + nc[u] * noise[u]
//   c[u][v] = sqrtP[v] * (sum_n H[n,u] W[n,v]) / amp[u]
//   nc[u]   = stddev[u] / amp[u],  amp[u] = sqrtP[u] * sum_n H[n,u] W[n,u]
__global__ __launch_bounds__(THREADS) void mix_kernel(
    const f32x4* __restrict__ x4,   // [U][BC4]
    const f32x4* __restrict__ n4,   // [U][BC4]
    const float* __restrict__ W,    // [NT][U]
    const float* __restrict__ H,    // [NT][U]
    const float* __restrict__ P,    // [U]
    const float* __restrict__ stddev, // [U]
    f32x4* __restrict__ o4)         // [U][BC4]
{
    // ---- per-thread coefficient computation (uniform addresses -> SGPRs) ----
    float c[UU][UU], nc[UU];
    {
        float sqrtP[UU];
#pragma unroll
        for (int v = 0; v < UU; ++v) sqrtP[v] = sqrtf(P[v]);
#pragma unroll
        for (int u = 0; u < UU; ++u) {
            float hw = 0.0f;
#pragma unroll
            for (int n = 0; n < NTT; ++n) hw += H[n * UU + u] * W[n * UU + u];
            const float inv_amp = 1.0f / (sqrtP[u] * hw);
#pragma unroll
            for (int v = 0; v < UU; ++v) {
                float m = 0.0f;
#pragma unroll
                for (int n = 0; n < NTT; ++n) m += H[n * UU + u] * W[n * UU + v];
                c[u][v] = m * sqrtP[v] * inv_amp;
            }
            nc[u] = stddev[u] * inv_amp;
        }
    }

    // ---- memory-bound mixing: one float4 per plane per thread ----
    const int i4 = blockIdx.x * THREADS + threadIdx.x;

    // Issue ALL 8 loads before any compute/store: max loads in flight.
    f32x4 xv[UU], nv[UU];
#pragma unroll
    for (int v = 0; v < UU; ++v)
        xv[v] = __builtin_nontemporal_load(&x4[v * BC4 + i4]);
#pragma unroll
    for (int u = 0; u < UU; ++u)
        nv[u] = __builtin_nontemporal_load(&n4[u * BC4 + i4]);

    f32x4 acc[UU];
#pragma unroll
    for (int u = 0; u < UU; ++u) {
        acc[u] = nc[u] * nv[u];
#pragma unroll
        for (int v = 0; v < UU; ++v)
            acc[u] += c[u][v] * xv[v];
    }

#pragma unroll
    for (int u = 0; u < UU; ++u)
        __builtin_nontemporal_store(acc[u], &o4[u * BC4 + i4]);
}

extern "C" void kernel_launch(void* const* d_in, const int* in_sizes, int n_in,
                              void* d_out, int out_size, void* d_ws, size_t ws_size,
                              hipStream_t stream) {
    const float* x      = (const float*)d_in[0];
    const float* W      = (const float*)d_in[1];
    const float* H      = (const float*)d_in[2];
    const float* P      = (const float*)d_in[3];
    const float* stddev = (const float*)d_in[4];
    const float* noise  = (const float*)d_in[5];
    float* out = (float*)d_out;

    mix_kernel<<<NBLOCKS, THREADS, 0, stream>>>(
        (const f32x4*)x, (const f32x4*)noise, W, H, P, stddev, (f32x4*)out);
}